// Round 10
// baseline (482.172 us; speedup 1.0000x reference)
//
#include <hip/hip_runtime.h>
#include <hip/hip_bf16.h>
#include <math.h>

typedef __bf16 bf16;
typedef bf16 bf16x4 __attribute__((ext_vector_type(4)));
typedef bf16 bf16x8 __attribute__((ext_vector_type(8)));
typedef float f32x4 __attribute__((ext_vector_type(4)));

#define AS1 __attribute__((address_space(1)))
#define AS3 __attribute__((address_space(3)))

// ---------------------------------------------------------------------------
// Transpose + f32->bf16 cast: src (R x C) f32 row-major -> dst (C x R) bf16.
// ---------------------------------------------------------------------------
__global__ __launch_bounds__(256) void k_transpose(const float* __restrict__ src,
                                                   bf16* __restrict__ dst,
                                                   int R, int C, int dstStride) {
    __shared__ float tile[32][33];
    int bc = blockIdx.x * 32, br = blockIdx.y * 32;
    int tx = threadIdx.x & 31, ty = threadIdx.x >> 5;
    for (int i = 0; i < 4; i++) {
        int r = ty + i * 8;
        tile[r][tx] = src[(size_t)(br + r) * C + bc + tx];
    }
    __syncthreads();
    for (int i = 0; i < 4; i++) {
        int r = ty + i * 8;
        dst[(size_t)(bc + r) * dstStride + br + tx] = (bf16)tile[tx][r];
    }
}

// ---------------------------------------------------------------------------
// LayerNorm: per-token mean/var over H=2048, write bf16 xn.
// ---------------------------------------------------------------------------
__global__ __launch_bounds__(256) void k_ln(const float* __restrict__ x,
                                            const float* __restrict__ w,
                                            const float* __restrict__ b,
                                            bf16* __restrict__ xn) {
    int s = blockIdx.x;
    int t = threadIdx.x;
    const float* row = x + (size_t)s * 2048;
    const float4* r4 = (const float4*)row;
    float4 A = r4[t * 2], B = r4[t * 2 + 1];
    float sum = A.x + A.y + A.z + A.w + B.x + B.y + B.z + B.w;
    float sq = A.x * A.x + A.y * A.y + A.z * A.z + A.w * A.w +
               B.x * B.x + B.y * B.y + B.z * B.z + B.w * B.w;
    for (int off = 32; off; off >>= 1) {
        sum += __shfl_down(sum, off);
        sq  += __shfl_down(sq, off);
    }
    __shared__ float rs[4], rq[4];
    if ((t & 63) == 0) { rs[t >> 6] = sum; rq[t >> 6] = sq; }
    __syncthreads();
    float S = rs[0] + rs[1] + rs[2] + rs[3];
    float Q = rq[0] + rq[1] + rq[2] + rq[3];
    float mu = S * (1.0f / 2048.0f);
    float var = Q * (1.0f / 2048.0f) - mu * mu;
    float rstd = rsqrtf(var + 1e-5f);
    float vals[8] = {A.x, A.y, A.z, A.w, B.x, B.y, B.z, B.w};
    bf16x8 ov;
    int j0 = t * 8;
    for (int i = 0; i < 8; i++)
        ov[i] = (bf16)((vals[i] - mu) * rstd * w[j0 + i] + b[j0 + i]);
    *(bf16x8*)&xn[(size_t)s * 2048 + j0] = ov;
}

// ---------------------------------------------------------------------------
// MFMA bf16 GEMM, 2-phase pipelined + T2 swizzle (round-9, proven).
// 128x128 tile, used for qkv and wo.
// ---------------------------------------------------------------------------
template <int MODE>
__global__ __launch_bounds__(256) void k_gemm(const bf16* __restrict__ A,
                                              const bf16* __restrict__ Bt,
                                              int M, int N, int K, int kslice,
                                              float* __restrict__ Cf,
                                              bf16* __restrict__ Cb,
                                              const float* __restrict__ bias) {
    __shared__ bf16 As[2][128][64];
    __shared__ bf16 Bs[2][128][64];
    int t = threadIdx.x;
    int bm = blockIdx.y, bn = blockIdx.x, bz = blockIdx.z;
    int w = t >> 6, l = t & 63, lr = l & 15, lg = l >> 4;
    int wm = w >> 1, wn = w & 1;
    f32x4 acc[4][4] = {};
    const bf16* Ab = A + (size_t)(bm * 128) * K + (size_t)bz * kslice;
    const bf16* Bb = Bt + (size_t)(bn * 128) * K + (size_t)bz * kslice;
    int srow = t >> 3;
    int scol = ((t & 7) ^ (srow & 7)) * 8;
    int nkt = kslice >> 6;

    auto STAGE = [&](int kt, int buf) {
        int k0 = kt * 64;
#pragma unroll
        for (int i = 0; i < 4; i++) {
            const bf16* ga = Ab + (size_t)(i * 32 + srow) * K + k0 + scol;
            const bf16* gb = Bb + (size_t)(i * 32 + srow) * K + k0 + scol;
            char* la = (char*)(&As[buf][0][0]) + i * 4096 + w * 1024;
            char* lb = (char*)(&Bs[buf][0][0]) + i * 4096 + w * 1024;
            __builtin_amdgcn_global_load_lds(
                (const AS1 void*)ga, (AS3 void*)la, 16, 0, 0);
            __builtin_amdgcn_global_load_lds(
                (const AS1 void*)gb, (AS3 void*)lb, 16, 0, 0);
        }
    };

    int sw = (lr & 7) << 4;

    STAGE(0, 0);
    for (int kt = 0; kt < nkt; ++kt) {
        int cur = kt & 1;
        if (kt + 1 < nkt) {
            STAGE(kt + 1, cur ^ 1);
            asm volatile("s_waitcnt vmcnt(8) lgkmcnt(0)" ::: "memory");
        } else {
            asm volatile("s_waitcnt vmcnt(0) lgkmcnt(0)" ::: "memory");
        }
        __builtin_amdgcn_s_barrier();
        asm volatile("" ::: "memory");
        const char* Abase = (const char*)&As[cur][0][0];
        const char* Bbase = (const char*)&Bs[cur][0][0];
#pragma unroll
        for (int kk = 0; kk < 2; kk++) {
            bf16x8 a[4], b[4];
            for (int fm = 0; fm < 4; fm++)
                a[fm] = *(const bf16x8*)(Abase + (wm * 64 + fm * 16 + lr) * 128 +
                                         ((kk * 64 + lg * 16) ^ sw));
            for (int fn = 0; fn < 4; fn++)
                b[fn] = *(const bf16x8*)(Bbase + (wn * 64 + fn * 16 + lr) * 128 +
                                         ((kk * 64 + lg * 16) ^ sw));
            for (int fm = 0; fm < 4; fm++)
                for (int fn = 0; fn < 4; fn++)
                    acc[fm][fn] = __builtin_amdgcn_mfma_f32_16x16x32_bf16(
                        a[fm], b[fn], acc[fm][fn], 0, 0, 0);
        }
        asm volatile("" ::: "memory");
        __builtin_amdgcn_s_barrier();
    }
    float* Cz = Cf + (size_t)bz * M * N;
    for (int fm = 0; fm < 4; fm++)
        for (int fn = 0; fn < 4; fn++) {
            int col = bn * 128 + wn * 64 + fn * 16 + lr;
            for (int r = 0; r < 4; r++) {
                int row = bm * 128 + wm * 64 + fm * 16 + lg * 4 + r;
                size_t idx = (size_t)row * N + col;
                float v = acc[fm][fn][r];
                if constexpr (MODE == 0) {
                    Cz[idx] = v;
                } else {
                    v += bias[col];
                    float e = __expf(1.5957691216057308f * (v + 0.044715f * v * v * v));
                    float th = 1.0f - 2.0f / (e + 1.0f);
                    Cb[idx] = (bf16)(0.5f * v * (1.0f + th));
                }
            }
        }
}

// ---------------------------------------------------------------------------
// MFMA bf16 GEMM, 256x256 tile, 8-phase-style schedule (T3+T4+T2+T5).
// 512 threads = 8 waves (2M x 4N), wave tile 128x64, acc f32x4[8][4].
// LDS: 2 dbuf x (256x64) per operand = 128 KB. Per K-tile: 4 phases, each
// {ds_read changed frags -> (ph0: stage t+1, 8 gload_lds) -> barrier ->
//  lgkmcnt(0)+sched_barrier -> setprio(1) -> 16 MFMA -> setprio(0) ->
//  (ph3: vmcnt(0), ~3 phases of cover) -> barrier}.
// Quadrants (qm,qn): (0,0),(0,1),(1,1),(1,0) -> 12/4/8/4 ds_reads per phase.
// Split-K via blockIdx.z; slices >=2 write to Cf2 (ws aliasing).
// MODE 0: Cf = acc. MODE 1: Cb = gelu_tanh(acc + bias).
// ---------------------------------------------------------------------------
template <int MODE>
__global__ __launch_bounds__(512, 2) void k_gemm256(const bf16* __restrict__ A,
                                                    const bf16* __restrict__ Bt,
                                                    int M, int N, int K, int kslice,
                                                    float* __restrict__ Cf,
                                                    float* __restrict__ Cf2,
                                                    bf16* __restrict__ Cb,
                                                    const float* __restrict__ bias) {
    __shared__ bf16 As[2][256][64];
    __shared__ bf16 Bs[2][256][64];
    int t = threadIdx.x;
    int w = t >> 6, l = t & 63, lr = l & 15, lg = l >> 4;
    int wm = w >> 2, wn = w & 3;
    int bm = blockIdx.y, bn = blockIdx.x, bz = blockIdx.z;
    f32x4 acc[8][4] = {};
    const bf16* Ab = A + (size_t)(bm * 256) * K + (size_t)bz * kslice;
    const bf16* Bb = Bt + (size_t)(bn * 256) * K + (size_t)bz * kslice;
    int srow = t >> 3;                      // 0..63
    int scol = ((t & 7) ^ (srow & 7)) * 8;  // pre-swizzled source col (elems)
    int nkt = kslice >> 6;
    int sw = (lr & 7) << 4;

    auto STAGE = [&](int kt, int buf) {
        int k0 = kt * 64;
#pragma unroll
        for (int i = 0; i < 4; i++) {
            const bf16* ga = Ab + (size_t)(i * 64 + srow) * K + k0 + scol;
            const bf16* gb = Bb + (size_t)(i * 64 + srow) * K + k0 + scol;
            char* la = (char*)(&As[buf][0][0]) + (i * 64 + w * 8) * 128;
            char* lb = (char*)(&Bs[buf][0][0]) + (i * 64 + w * 8) * 128;
            __builtin_amdgcn_global_load_lds(
                (const AS1 void*)ga, (AS3 void*)la, 16, 0, 0);
            __builtin_amdgcn_global_load_lds(
                (const AS1 void*)gb, (AS3 void*)lb, 16, 0, 0);
        }
    };

    STAGE(0, 0);
    asm volatile("s_waitcnt vmcnt(0)" ::: "memory");
    __builtin_amdgcn_s_barrier();
    asm volatile("" ::: "memory");

    for (int kt = 0; kt < nkt; ++kt) {
        int cur = kt & 1;
        const char* Abase = (const char*)&As[cur][0][0] + (wm * 128) * 128;
        const char* Bbase = (const char*)&Bs[cur][0][0] + (wn * 64) * 128;
        bf16x8 a[4][2], b[2][2];
#pragma unroll
        for (int ph = 0; ph < 4; ++ph) {
            const int qm = ph >> 1;                    // 0,0,1,1
            const int qn = (ph == 1 || ph == 2) ? 1 : 0;  // 0,1,1,0
            if (ph == 0 || ph == 2) {
#pragma unroll
                for (int fm = 0; fm < 4; fm++)
#pragma unroll
                    for (int kk = 0; kk < 2; kk++)
                        a[fm][kk] = *(const bf16x8*)(Abase +
                            (qm * 64 + fm * 16 + lr) * 128 +
                            ((kk * 64 + lg * 16) ^ sw));
            }
            if (ph != 2) {
#pragma unroll
                for (int fn = 0; fn < 2; fn++)
#pragma unroll
                    for (int kk = 0; kk < 2; kk++)
                        b[fn][kk] = *(const bf16x8*)(Bbase +
                            (qn * 32 + fn * 16 + lr) * 128 +
                            ((kk * 64 + lg * 16) ^ sw));
            }
            if (ph == 0 && kt + 1 < nkt) STAGE(kt + 1, cur ^ 1);
            __builtin_amdgcn_s_barrier();
            asm volatile("s_waitcnt lgkmcnt(0)" ::: "memory");
            __builtin_amdgcn_sched_barrier(0);
            __builtin_amdgcn_s_setprio(1);
#pragma unroll
            for (int fm = 0; fm < 4; fm++)
#pragma unroll
                for (int fn = 0; fn < 2; fn++)
#pragma unroll
                    for (int kk = 0; kk < 2; kk++)
                        acc[qm * 4 + fm][qn * 2 + fn] =
                            __builtin_amdgcn_mfma_f32_16x16x32_bf16(
                                a[fm][kk], b[fn][kk],
                                acc[qm * 4 + fm][qn * 2 + fn], 0, 0, 0);
            __builtin_amdgcn_s_setprio(0);
            if (ph == 3) asm volatile("s_waitcnt vmcnt(0)" ::: "memory");
            asm volatile("" ::: "memory");
            __builtin_amdgcn_s_barrier();
        }
    }

    float* Cz = ((bz < 2) ? Cf : Cf2) + (size_t)(bz & 1) * M * N;
#pragma unroll
    for (int mi = 0; mi < 8; mi++)
#pragma unroll
        for (int ni = 0; ni < 4; ni++) {
            int col = bn * 256 + wn * 64 + (ni >> 1) * 32 + (ni & 1) * 16 + lr;
            for (int r = 0; r < 4; r++) {
                int row = bm * 256 + wm * 128 + (mi >> 2) * 64 + (mi & 3) * 16 +
                          lg * 4 + r;
                size_t idx = (size_t)row * N + col;
                float v = acc[mi][ni][r];
                if constexpr (MODE == 0) {
                    Cz[idx] = v;
                } else {
                    v += bias[col];
                    float e = __expf(1.5957691216057308f * (v + 0.044715f * v * v * v));
                    float th = 1.0f - 2.0f / (e + 1.0f);
                    Cb[idx] = (bf16)(0.5f * v * (1.0f + th));
                }
            }
        }
}

// ---------------------------------------------------------------------------
// Final fuse: out = hidden + (W0+W1) + (P0+P1+P2+P3) + down_b.
// ---------------------------------------------------------------------------
__global__ __launch_bounds__(256) void k_final(const float* __restrict__ hidden,
                                               const float* __restrict__ w0,
                                               const float* __restrict__ w1,
                                               const float* __restrict__ p0,
                                               const float* __restrict__ p1,
                                               const float* __restrict__ p2,
                                               const float* __restrict__ p3,
                                               const float* __restrict__ bias,
                                               float* __restrict__ out) {
    int idx = blockIdx.x * 256 + threadIdx.x;
    int col4 = idx & 511;
    float4 b = ((const float4*)bias)[col4];
    float4 h = ((const float4*)hidden)[idx];
    float4 a0 = ((const float4*)w0)[idx];
    float4 a1 = ((const float4*)w1)[idx];
    float4 d0 = ((const float4*)p0)[idx];
    float4 d1 = ((const float4*)p1)[idx];
    float4 d2 = ((const float4*)p2)[idx];
    float4 d3 = ((const float4*)p3)[idx];
    float4 o;
    o.x = h.x + a0.x + a1.x + d0.x + d1.x + d2.x + d3.x + b.x;
    o.y = h.y + a0.y + a1.y + d0.y + d1.y + d2.y + d3.y + b.y;
    o.z = h.z + a0.z + a1.z + d0.z + d1.z + d2.z + d3.z + b.z;
    o.w = h.w + a0.w + a1.w + d0.w + d1.w + d2.w + d3.w + b.w;
    ((float4*)out)[idx] = o;
}

// ---------------------------------------------------------------------------
// tau weights per token (position_ids arrive as int32 from the harness).
// ---------------------------------------------------------------------------
__global__ __launch_bounds__(256) void k_tau(const float* __restrict__ qkv,
                                             const float* __restrict__ twq,
                                             const float* __restrict__ twv,
                                             const float* __restrict__ alpha,
                                             const int* __restrict__ pos,
                                             float* __restrict__ tauq,
                                             float* __restrict__ tauv) {
    int s = blockIdx.x;
    __shared__ float tok[3072];
    __shared__ float part[4][64];
    const float* row = qkv + (size_t)s * 3072;
    for (int j = threadIdx.x; j < 3072; j += 256) {
        float x = row[j];
        tok[j] = x * 0.5f * (1.0f + erff(x * 0.7071067811865475f));
    }
    __syncthreads();
    int h = threadIdx.x & 63;
    int chunk = threadIdx.x >> 6;
    const float* W = (h < 32) ? twq : twv;
    int hh = h & 31;
    float acc = 0.0f;
    int j0 = chunk * 768;
    for (int j = j0; j < j0 + 768; ++j) acc += tok[j] * W[j * 32 + hh];
    part[chunk][h] = acc;
    __syncthreads();
    if (chunk == 0) {
        float tot = part[0][h] + part[1][h] + part[2][h] + part[3][h];
        float pf = (float)(pos[s] + 1);
        float lp = logf(pf);
        float tp = 1.0f + (1.0f / (1.0f + expf(-alpha[hh] * lp)) - 0.5f);
        float val = tanhf(tot) + tp;
        if (h < 32) tauq[s * 32 + hh] = val;
        else        tauv[s * 32 + hh] = val;
    }
}

// ---------------------------------------------------------------------------
// Head build: RoPE + tau scaling; Vt stored (kvh*64+d, s).
// ---------------------------------------------------------------------------
__global__ __launch_bounds__(256) void k_heads(const float* __restrict__ qkv,
                                               const float* __restrict__ cosb,
                                               const float* __restrict__ sinb,
                                               const float* __restrict__ tauq,
                                               const float* __restrict__ tauv,
                                               bf16* __restrict__ Qr,
                                               bf16* __restrict__ Kr,
                                               bf16* __restrict__ Vt) {
    int s = blockIdx.x * 4 + (threadIdx.x >> 6);
    int d = threadIdx.x & 63;
    int j = (d >> 1) & 15;
    float c = cosb[s * 16 + j], sn = sinb[s * 16 + j];
    const float* row = qkv + (size_t)s * 3072;
    for (int h = 0; h < 32; ++h) {
        float x = row[h * 64 + d] * tauq[s * 32 + h] * 0.125f;
        float xr = __shfl(x, j);
        float xi = __shfl(x, j + 16);
        float out = (d < 32) ? ((d & 1) ? (xr * sn + xi * c) : (xr * c - xi * sn)) : x;
        Qr[(size_t)s * 2048 + h * 64 + d] = (bf16)out;
    }
    for (int h = 0; h < 8; ++h) {
        float x = row[2048 + h * 64 + d];
        float xr = __shfl(x, j);
        float xi = __shfl(x, j + 16);
        float out = (d < 32) ? ((d & 1) ? (xr * sn + xi * c) : (xr * c - xi * sn)) : x;
        Kr[(size_t)s * 512 + h * 64 + d] = (bf16)out;
    }
    for (int h = 0; h < 8; ++h) {
        float x = row[2560 + h * 64 + d] * tauv[s * 32 + h];
        Vt[((size_t)h * 64 + d) * 2048 + s] = (bf16)x;
    }
}

// ---------------------------------------------------------------------------
// Flash attention v5 (causal, GQA 32/8, D=64): block-cooperative (round 7).
// ---------------------------------------------------------------------------
__global__ __launch_bounds__(512, 4) void k_attn(const bf16* __restrict__ Q,
                                                 const bf16* __restrict__ K,
                                                 const bf16* __restrict__ Vt,
                                                 bf16* __restrict__ O) {
    __shared__ bf16 Ks[2][64][64];
    __shared__ bf16 Vs[2][64][64];
    __shared__ bf16 plds[8][16][72];
    int t = threadIdx.x;
    int w = t >> 6, l = t & 63, lr = l & 15, lg = l >> 4;
    int h = blockIdx.x, kvh = h >> 2;
    int qb = 15 - blockIdx.y;
    int qrow0 = qb * 128 + w * 16;
    int qg = qrow0 + lr;
    int qmax = qrow0 + 15;
    int nkt = 2 * qb + 2;

    int srow = t >> 3;
    int scol = ((t & 7) * 16) ^ ((srow & 7) << 4);
    const char* gK = (const char*)(K + (size_t)kvh * 64);
    const char* gV = (const char*)(Vt + (size_t)kvh * 64 * 2048);
    char* ldsK = (char*)&Ks[0][0][0] + w * 1024;
    char* ldsV = (char*)&Vs[0][0][0] + w * 1024;

    bf16x8 q0 = *(const bf16x8*)&Q[(size_t)qg * 2048 + h * 64 + lg * 8];
    bf16x8 q1 = *(const bf16x8*)&Q[(size_t)qg * 2048 + h * 64 + 32 + lg * 8];
    f32x4 o[4] = {};
    float m = -3e38f, ll = 0.0f;
    int sw = (lr & 7) << 4;

    __builtin_amdgcn_global_load_lds(
        (const AS1 void*)(gK + (size_t)srow * 1024 + scol), (AS3 void*)ldsK, 16, 0, 0);
    __builtin_amdgcn_global_load_lds(
        (const AS1 void*)(gV + (size_t)srow * 4096 + scol), (AS3 void*)ldsV, 16, 0, 0);
    __syncthreads();

    for (int kt = 0; kt < nkt; ++kt) {
        int kb = kt * 64;
        int cur = kt & 1, nxt = cur ^ 1;
        if (kt + 1 < nkt) {
            int kb2 = kb + 64;
            __builtin_amdgcn_global_load_lds(
                (const AS1 void*)(gK + (size_t)(kb2 + srow) * 1024 + scol),
                (AS3 void*)(ldsK + nxt * 8192), 16, 0, 0);
            __builtin_amdgcn_global_load_lds(
                (const AS1 void*)(gV + (size_t)srow * 4096 + kb2 * 2 + scol),
                (AS3 void*)(ldsV + nxt * 8192), 16, 0, 0);
        }
        if (kb <= qmax) {
            const char* Kbuf = (const char*)Ks + cur * 8192;
            const char* Vbuf = (const char*)Vs + cur * 8192;
            f32x4 sc[2][2];
#pragma unroll
            for (int ks = 0; ks < 2; ks++)
                for (int kc = 0; kc < 2; kc++) {
                    int krow = ks * 32 + kc * 16 + lr;
                    bf16x8 k0 = *(const bf16x8*)(Kbuf + krow * 128 + ((lg * 16) ^ sw));
                    bf16x8 k1 = *(const bf16x8*)(Kbuf + krow * 128 + ((64 + lg * 16) ^ sw));
                    f32x4 z = {};
                    z = __builtin_amdgcn_mfma_f32_16x16x32_bf16(k0, q0, z, 0, 0, 0);
                    sc[ks][kc] = __builtin_amdgcn_mfma_f32_16x16x32_bf16(k1, q1, z, 0, 0, 0);
                }
            if (kb + 63 > qrow0) {
#pragma unroll
                for (int ks = 0; ks < 2; ks++)
                    for (int kc = 0; kc < 2; kc++)
                        for (int r = 0; r < 4; r++) {
                            int kg = kb + ks * 32 + kc * 16 + lg * 4 + r;
                            if (kg > qg) sc[ks][kc][r] = -1e30f;
                        }
            }
            float tmax = -3e38f;
#pragma unroll
            for (int ks = 0; ks < 2; ks++)
                for (int kc = 0; kc < 2; kc++)
                    for (int r = 0; r < 4; r++) tmax = fmaxf(tmax, sc[ks][kc][r]);
            tmax = fmaxf(tmax, __shfl_xor(tmax, 16));
            tmax = fmaxf(tmax, __shfl_xor(tmax, 32));
            if (!__all(tmax <= m)) {
                float mn = fmaxf(m, tmax);
                float al = __expf(m - mn);
                m = mn;
                ll *= al;
#pragma unroll
                for (int fn = 0; fn < 4; fn++)
                    for (int r = 0; r < 4; r++) o[fn][r] *= al;
            }
            float rsum = 0.0f;
#pragma unroll
            for (int ks = 0; ks < 2; ks++)
                for (int kc = 0; kc < 2; kc++) {
                    bf16x4 pk;
                    for (int r = 0; r < 4; r++) {
                        float pv = __expf(sc[ks][kc][r] - m);
                        rsum += pv;
                        pk[r] = (bf16)pv;
                    }
                    *(bf16x4*)&plds[w][lr][ks * 32 + kc * 16 + lg * 4] = pk;
                }
            ll += rsum;
            bf16x8 vf[2][4];
#pragma unroll
            for (int ks = 0; ks < 2; ks++)
                for (int fn = 0; fn < 4; fn++) {
                    int drow = fn * 16 + lr;
                    vf[ks][fn] = *(const bf16x8*)(Vbuf + drow * 128 + ((ks * 64 + lg * 16) ^ sw));
                }
            asm volatile("s_waitcnt lgkmcnt(0)" ::: "memory");
            __builtin_amdgcn_sched_barrier(0);
            bf16x8 pa0 = *(const bf16x8*)&plds[w][lr][lg * 8];
            bf16x8 pa1 = *(const bf16x8*)&plds[w][lr][32 + lg * 8];
#pragma unroll
            for (int fn = 0; fn < 4; fn++)
                o[fn] = __builtin_amdgcn_mfma_f32_16x16x32_bf16(vf[0][fn], pa0, o[fn], 0, 0, 0);
#pragma unroll
            for (int fn = 0; fn < 4; fn++)
                o[fn] = __builtin_amdgcn_mfma_f32_16x16x32_bf16(vf[1][fn], pa1, o[fn], 0, 0, 0);
        }
        __syncthreads();
    }

    ll += __shfl_xor(ll, 16);
    ll += __shfl_xor(ll, 32);
    float rinv = 1.0f / ll;
    for (int fn = 0; fn < 4; fn++) {
        bf16x4 ov;
        for (int r = 0; r < 4; r++) ov[r] = (bf16)(o[fn][r] * rinv);
        *(bf16x4*)&O[(size_t)qg * 2048 + h * 64 + fn * 16 + lg * 4] = ov;
    }
}

// ---------------------------------------------------------------------------
extern "C" void kernel_launch(void* const* d_in, const int* in_sizes, int n_in,
                              void* d_out, int out_size, void* d_ws, size_t ws_size,
                              hipStream_t stream) {
    const float* hidden = (const float*)d_in[0];
    const int*   pos    = (const int*)d_in[1];   // harness converts int64 -> int32
    const float* cosb   = (const float*)d_in[2];
    const float* sinb   = (const float*)d_in[3];
    const float* ln_w   = (const float*)d_in[4];
    const float* ln_b   = (const float*)d_in[5];
    const float* wq     = (const float*)d_in[6];
    const float* wk     = (const float*)d_in[7];
    const float* wv     = (const float*)d_in[8];
    const float* wo     = (const float*)d_in[9];
    const float* twq    = (const float*)d_in[10];
    const float* twv    = (const float*)d_in[11];
    const float* alpha  = (const float*)d_in[12];
    const float* up_w   = (const float*)d_in[13];
    const float* up_b   = (const float*)d_in[14];
    const float* down_w = (const float*)d_in[15];
    const float* down_b = (const float*)d_in[16];
    float* out = (float*)d_out;

    char* p = (char*)d_ws;
    auto alloc = [&](size_t n) -> char* {
        char* r = p;
        p += (n + 255) & ~(size_t)255;
        return r;
    };
    bf16* wqkvT = (bf16*)alloc((size_t)3072 * 2048 * 2);
    bf16* woT   = (bf16*)alloc((size_t)2048 * 2048 * 2);
    bf16* upT   = (bf16*)alloc((size_t)8192 * 2048 * 2);
    bf16* downT = (bf16*)alloc((size_t)2048 * 8192 * 2);
    bf16* xn    = (bf16*)alloc((size_t)2048 * 2048 * 2);
    float* qkv  = (float*)alloc((size_t)2048 * 3072 * 4);   // dead after k_heads
    float* tauq = (float*)alloc((size_t)2048 * 32 * 4);     // dead after k_heads
    float* tauv = (float*)alloc((size_t)2048 * 32 * 4);     // dead after k_heads
    bf16* Qr    = (bf16*)alloc((size_t)2048 * 2048 * 2);    // dead after k_attn
    bf16* Kr    = (bf16*)alloc((size_t)2048 * 512 * 2);
    bf16* Vt    = (bf16*)alloc((size_t)8 * 64 * 2048 * 2);
    bf16* aout  = (bf16*)alloc((size_t)2048 * 2048 * 2);
    bf16* hbuf  = (bf16*)alloc((size_t)2048 * 8192 * 2);
    float* Wp   = (float*)alloc((size_t)2 * 2048 * 2048 * 4);
    float* Pp   = (float*)alloc((size_t)2 * 2048 * 2048 * 4);
    // down split-K slices 2,3 alias the dead qkv..Qr region (34.08 MB >= 33.55)
    float* PpX  = qkv;

    k_transpose<<<dim3(64, 64), 256, 0, stream>>>(wq, wqkvT, 2048, 2048, 2048);
    k_transpose<<<dim3(16, 64), 256, 0, stream>>>(wk, wqkvT + (size_t)2048 * 2048, 2048, 512, 2048);
    k_transpose<<<dim3(16, 64), 256, 0, stream>>>(wv, wqkvT + (size_t)2560 * 2048, 2048, 512, 2048);
    k_transpose<<<dim3(64, 64), 256, 0, stream>>>(wo, woT, 2048, 2048, 2048);
    k_transpose<<<dim3(256, 64), 256, 0, stream>>>(up_w, upT, 2048, 8192, 2048);
    k_transpose<<<dim3(64, 256), 256, 0, stream>>>(down_w, downT, 8192, 2048, 8192);

    k_ln<<<2048, 256, 0, stream>>>(hidden, ln_w, ln_b, xn);

    // qkv = xn @ [wq|wk|wv]   (128² 2-phase)
    k_gemm<0><<<dim3(24, 16, 1), 256, 0, stream>>>(xn, wqkvT, 2048, 3072, 2048, 2048,
                                                   qkv, nullptr, nullptr);

    k_tau<<<2048, 256, 0, stream>>>(qkv, twq, twv, alpha, pos, tauq, tauv);
    k_heads<<<512, 256, 0, stream>>>(qkv, cosb, sinb, tauq, tauv, Qr, Kr, Vt);

    k_attn<<<dim3(32, 16), 512, 0, stream>>>(Qr, Kr, Vt, aout);

    // wo partials: aout @ woT, split-K 2 (128² 2-phase)
    k_gemm<0><<<dim3(16, 16, 2), 256, 0, stream>>>(aout, woT, 2048, 2048, 2048, 1024,
                                                   Wp, nullptr, nullptr);
    // h = gelu_tanh(xn @ up_w + up_b)   (256² 8-phase; 256 blocks = 1/CU)
    k_gemm256<1><<<dim3(32, 8, 1), 512, 0, stream>>>(xn, upT, 2048, 8192, 2048, 2048,
                                                     nullptr, nullptr, hbuf, up_b);
    // down partials: hbuf @ downT, split-K 4 (256² 8-phase; 256 blocks)
    k_gemm256<0><<<dim3(8, 8, 4), 512, 0, stream>>>(hbuf, downT, 2048, 2048, 8192, 2048,
                                                    Pp, PpX, nullptr, nullptr);
    // out = hidden + W0+W1 + P0..P3 + down_b
    k_final<<<4096, 256, 0, stream>>>(hidden, Wp, Wp + (size_t)2048 * 2048,
                                      Pp, Pp + (size_t)2048 * 2048,
                                      PpX, PpX + (size_t)2048 * 2048, down_b, out);
}

// Round 11
// 467.833 us; speedup vs baseline: 1.0306x; 1.0306x over previous
//
#include <hip/hip_runtime.h>
#include <hip/hip_bf16.h>
#include <math.h>

typedef __bf16 bf16;
typedef bf16 bf16x4 __attribute__((ext_vector_type(4)));
typedef bf16 bf16x8 __attribute__((ext_vector_type(8)));
typedef float f32x4 __attribute__((ext_vector_type(4)));

#define AS1 __attribute__((address_space(1)))
#define AS3 __attribute__((address_space(3)))

// ---------------------------------------------------------------------------
// Transpose + f32->bf16 cast: src (R x C) f32 row-major -> dst (C x R) bf16.
// ---------------------------------------------------------------------------
__global__ __launch_bounds__(256) void k_transpose(const float* __restrict__ src,
                                                   bf16* __restrict__ dst,
                                                   int R, int C, int dstStride) {
    __shared__ float tile[32][33];
    int bc = blockIdx.x * 32, br = blockIdx.y * 32;
    int tx = threadIdx.x & 31, ty = threadIdx.x >> 5;
    for (int i = 0; i < 4; i++) {
        int r = ty + i * 8;
        tile[r][tx] = src[(size_t)(br + r) * C + bc + tx];
    }
    __syncthreads();
    for (int i = 0; i < 4; i++) {
        int r = ty + i * 8;
        dst[(size_t)(bc + r) * dstStride + br + tx] = (bf16)tile[tx][r];
    }
}

// ---------------------------------------------------------------------------
// LayerNorm: per-token mean/var over H=2048, write bf16 xn.
// ---------------------------------------------------------------------------
__global__ __launch_bounds__(256) void k_ln(const float* __restrict__ x,
                                            const float* __restrict__ w,
                                            const float* __restrict__ b,
                                            bf16* __restrict__ xn) {
    int s = blockIdx.x;
    int t = threadIdx.x;
    const float* row = x + (size_t)s * 2048;
    const float4* r4 = (const float4*)row;
    float4 A = r4[t * 2], B = r4[t * 2 + 1];
    float sum = A.x + A.y + A.z + A.w + B.x + B.y + B.z + B.w;
    float sq = A.x * A.x + A.y * A.y + A.z * A.z + A.w * A.w +
               B.x * B.x + B.y * B.y + B.z * B.z + B.w * B.w;
    for (int off = 32; off; off >>= 1) {
        sum += __shfl_down(sum, off);
        sq  += __shfl_down(sq, off);
    }
    __shared__ float rs[4], rq[4];
    if ((t & 63) == 0) { rs[t >> 6] = sum; rq[t >> 6] = sq; }
    __syncthreads();
    float S = rs[0] + rs[1] + rs[2] + rs[3];
    float Q = rq[0] + rq[1] + rq[2] + rq[3];
    float mu = S * (1.0f / 2048.0f);
    float var = Q * (1.0f / 2048.0f) - mu * mu;
    float rstd = rsqrtf(var + 1e-5f);
    float vals[8] = {A.x, A.y, A.z, A.w, B.x, B.y, B.z, B.w};
    bf16x8 ov;
    int j0 = t * 8;
    for (int i = 0; i < 8; i++)
        ov[i] = (bf16)((vals[i] - mu) * rstd * w[j0 + i] + b[j0 + i]);
    *(bf16x8*)&xn[(size_t)s * 2048 + j0] = ov;
}

// ---------------------------------------------------------------------------
// MFMA bf16 GEMM, m97-replica + T2 swizzle: C = A(MxK) @ Bt(NxK)^T.
// 128x128 tile, BK=64, SINGLE-buffered 32 KB LDS -> 4 blocks/CU: implicit
// wave-level overlap across blocks hides the serial stage->vmcnt(0)->barrier
// drain (m114 mechanism; explicit dbuf at 2 blocks/CU measured neutral).
// Staging: global_load_lds(16B), linear LDS dest, pre-swizzled global source
// (chunk ^= row&7); fragment read applies the same XOR -> 0 bank conflicts.
// Split-K via blockIdx.z. MODE 0: Cf = acc. MODE 1: Cb = gelu_tanh(acc+bias).
// ---------------------------------------------------------------------------
template <int MODE>
__global__ __launch_bounds__(256) void k_gemm(const bf16* __restrict__ A,
                                              const bf16* __restrict__ Bt,
                                              int M, int N, int K, int kslice,
                                              float* __restrict__ Cf,
                                              bf16* __restrict__ Cb,
                                              const float* __restrict__ bias) {
    __shared__ bf16 As[128][64];
    __shared__ bf16 Bs[128][64];
    int t = threadIdx.x;
    int bm = blockIdx.y, bn = blockIdx.x, bz = blockIdx.z;
    int w = t >> 6, l = t & 63, lr = l & 15, lg = l >> 4;
    int wm = w >> 1, wn = w & 1;
    f32x4 acc[4][4] = {};
    const bf16* Ab = A + (size_t)(bm * 128) * K + (size_t)bz * kslice;
    const bf16* Bb = Bt + (size_t)(bn * 128) * K + (size_t)bz * kslice;
    int srow = t >> 3;
    int scol = ((t & 7) ^ (srow & 7)) * 8;  // pre-swizzled source col (elems)
    int nkt = kslice >> 6;
    int sw = (lr & 7) << 4;

    for (int kt = 0; kt < nkt; ++kt) {
        int k0 = kt * 64;
        if (kt) __syncthreads();  // prior compute done reading LDS
#pragma unroll
        for (int i = 0; i < 4; i++) {
            const bf16* ga = Ab + (size_t)(i * 32 + srow) * K + k0 + scol;
            const bf16* gb = Bb + (size_t)(i * 32 + srow) * K + k0 + scol;
            char* la = (char*)(&As[0][0]) + i * 4096 + w * 1024;
            char* lb = (char*)(&Bs[0][0]) + i * 4096 + w * 1024;
            __builtin_amdgcn_global_load_lds(
                (const AS1 void*)ga, (AS3 void*)la, 16, 0, 0);
            __builtin_amdgcn_global_load_lds(
                (const AS1 void*)gb, (AS3 void*)lb, 16, 0, 0);
        }
        asm volatile("s_waitcnt vmcnt(0)" ::: "memory");
        __syncthreads();
        const char* Abase = (const char*)&As[0][0];
        const char* Bbase = (const char*)&Bs[0][0];
#pragma unroll
        for (int kk = 0; kk < 2; kk++) {
            bf16x8 a[4], b[4];
            for (int fm = 0; fm < 4; fm++)
                a[fm] = *(const bf16x8*)(Abase + (wm * 64 + fm * 16 + lr) * 128 +
                                         ((kk * 64 + lg * 16) ^ sw));
            for (int fn = 0; fn < 4; fn++)
                b[fn] = *(const bf16x8*)(Bbase + (wn * 64 + fn * 16 + lr) * 128 +
                                         ((kk * 64 + lg * 16) ^ sw));
            for (int fm = 0; fm < 4; fm++)
                for (int fn = 0; fn < 4; fn++)
                    acc[fm][fn] = __builtin_amdgcn_mfma_f32_16x16x32_bf16(
                        a[fm], b[fn], acc[fm][fn], 0, 0, 0);
        }
    }
    float* Cz = Cf + (size_t)bz * M * N;
    for (int fm = 0; fm < 4; fm++)
        for (int fn = 0; fn < 4; fn++) {
            int col = bn * 128 + wn * 64 + fn * 16 + lr;
            for (int r = 0; r < 4; r++) {
                int row = bm * 128 + wm * 64 + fm * 16 + lg * 4 + r;
                size_t idx = (size_t)row * N + col;
                float v = acc[fm][fn][r];
                if constexpr (MODE == 0) {
                    Cz[idx] = v;
                } else {
                    v += bias[col];
                    float e = __expf(1.5957691216057308f * (v + 0.044715f * v * v * v));
                    float th = 1.0f - 2.0f / (e + 1.0f);
                    Cb[idx] = (bf16)(0.5f * v * (1.0f + th));
                }
            }
        }
}

// ---------------------------------------------------------------------------
// Final fuse: out = hidden + (W0+W1) + (P0+P1) + down_b.
// ---------------------------------------------------------------------------
__global__ __launch_bounds__(256) void k_final(const float* __restrict__ hidden,
                                               const float* __restrict__ w0,
                                               const float* __restrict__ w1,
                                               const float* __restrict__ p0,
                                               const float* __restrict__ p1,
                                               const float* __restrict__ bias,
                                               float* __restrict__ out) {
    int idx = blockIdx.x * 256 + threadIdx.x;
    int col4 = idx & 511;
    float4 b = ((const float4*)bias)[col4];
    float4 h = ((const float4*)hidden)[idx];
    float4 a0 = ((const float4*)w0)[idx];
    float4 a1 = ((const float4*)w1)[idx];
    float4 d0 = ((const float4*)p0)[idx];
    float4 d1 = ((const float4*)p1)[idx];
    float4 o;
    o.x = h.x + a0.x + a1.x + d0.x + d1.x + b.x;
    o.y = h.y + a0.y + a1.y + d0.y + d1.y + b.y;
    o.z = h.z + a0.z + a1.z + d0.z + d1.z + b.z;
    o.w = h.w + a0.w + a1.w + d0.w + d1.w + b.w;
    ((float4*)out)[idx] = o;
}

// ---------------------------------------------------------------------------
// tau weights per token (position_ids arrive as int32 from the harness).
// ---------------------------------------------------------------------------
__global__ __launch_bounds__(256) void k_tau(const float* __restrict__ qkv,
                                             const float* __restrict__ twq,
                                             const float* __restrict__ twv,
                                             const float* __restrict__ alpha,
                                             const int* __restrict__ pos,
                                             float* __restrict__ tauq,
                                             float* __restrict__ tauv) {
    int s = blockIdx.x;
    __shared__ float tok[3072];
    __shared__ float part[4][64];
    const float* row = qkv + (size_t)s * 3072;
    for (int j = threadIdx.x; j < 3072; j += 256) {
        float x = row[j];
        tok[j] = x * 0.5f * (1.0f + erff(x * 0.7071067811865475f));
    }
    __syncthreads();
    int h = threadIdx.x & 63;
    int chunk = threadIdx.x >> 6;
    const float* W = (h < 32) ? twq : twv;
    int hh = h & 31;
    float acc = 0.0f;
    int j0 = chunk * 768;
    for (int j = j0; j < j0 + 768; ++j) acc += tok[j] * W[j * 32 + hh];
    part[chunk][h] = acc;
    __syncthreads();
    if (chunk == 0) {
        float tot = part[0][h] + part[1][h] + part[2][h] + part[3][h];
        float pf = (float)(pos[s] + 1);
        float lp = logf(pf);
        float tp = 1.0f + (1.0f / (1.0f + expf(-alpha[hh] * lp)) - 0.5f);
        float val = tanhf(tot) + tp;
        if (h < 32) tauq[s * 32 + hh] = val;
        else        tauv[s * 32 + hh] = val;
    }
}

// ---------------------------------------------------------------------------
// Head build: RoPE + tau scaling; Vt stored (kvh*64+d, s).
// ---------------------------------------------------------------------------
__global__ __launch_bounds__(256) void k_heads(const float* __restrict__ qkv,
                                               const float* __restrict__ cosb,
                                               const float* __restrict__ sinb,
                                               const float* __restrict__ tauq,
                                               const float* __restrict__ tauv,
                                               bf16* __restrict__ Qr,
                                               bf16* __restrict__ Kr,
                                               bf16* __restrict__ Vt) {
    int s = blockIdx.x * 4 + (threadIdx.x >> 6);
    int d = threadIdx.x & 63;
    int j = (d >> 1) & 15;
    float c = cosb[s * 16 + j], sn = sinb[s * 16 + j];
    const float* row = qkv + (size_t)s * 3072;
    for (int h = 0; h < 32; ++h) {
        float x = row[h * 64 + d] * tauq[s * 32 + h] * 0.125f;
        float xr = __shfl(x, j);
        float xi = __shfl(x, j + 16);
        float out = (d < 32) ? ((d & 1) ? (xr * sn + xi * c) : (xr * c - xi * sn)) : x;
        Qr[(size_t)s * 2048 + h * 64 + d] = (bf16)out;
    }
    for (int h = 0; h < 8; ++h) {
        float x = row[2048 + h * 64 + d];
        float xr = __shfl(x, j);
        float xi = __shfl(x, j + 16);
        float out = (d < 32) ? ((d & 1) ? (xr * sn + xi * c) : (xr * c - xi * sn)) : x;
        Kr[(size_t)s * 512 + h * 64 + d] = (bf16)out;
    }
    for (int h = 0; h < 8; ++h) {
        float x = row[2560 + h * 64 + d] * tauv[s * 32 + h];
        Vt[((size_t)h * 64 + d) * 2048 + s] = (bf16)x;
    }
}

// ---------------------------------------------------------------------------
// Flash attention v5 (causal, GQA 32/8, D=64): block-cooperative (round 7).
// ---------------------------------------------------------------------------
__global__ __launch_bounds__(512, 4) void k_attn(const bf16* __restrict__ Q,
                                                 const bf16* __restrict__ K,
                                                 const bf16* __restrict__ Vt,
                                                 bf16* __restrict__ O) {
    __shared__ bf16 Ks[2][64][64];
    __shared__ bf16 Vs[2][64][64];
    __shared__ bf16 plds[8][16][72];
    int t = threadIdx.x;
    int w = t >> 6, l = t & 63, lr = l & 15, lg = l >> 4;
    int h = blockIdx.x, kvh = h >> 2;
    int qb = 15 - blockIdx.y;
    int qrow0 = qb * 128 + w * 16;
    int qg = qrow0 + lr;
    int qmax = qrow0 + 15;
    int nkt = 2 * qb + 2;

    int srow = t >> 3;
    int scol = ((t & 7) * 16) ^ ((srow & 7) << 4);
    const char* gK = (const char*)(K + (size_t)kvh * 64);
    const char* gV = (const char*)(Vt + (size_t)kvh * 64 * 2048);
    char* ldsK = (char*)&Ks[0][0][0] + w * 1024;
    char* ldsV = (char*)&Vs[0][0][0] + w * 1024;

    bf16x8 q0 = *(const bf16x8*)&Q[(size_t)qg * 2048 + h * 64 + lg * 8];
    bf16x8 q1 = *(const bf16x8*)&Q[(size_t)qg * 2048 + h * 64 + 32 + lg * 8];
    f32x4 o[4] = {};
    float m = -3e38f, ll = 0.0f;
    int sw = (lr & 7) << 4;

    __builtin_amdgcn_global_load_lds(
        (const AS1 void*)(gK + (size_t)srow * 1024 + scol), (AS3 void*)ldsK, 16, 0, 0);
    __builtin_amdgcn_global_load_lds(
        (const AS1 void*)(gV + (size_t)srow * 4096 + scol), (AS3 void*)ldsV, 16, 0, 0);
    __syncthreads();

    for (int kt = 0; kt < nkt; ++kt) {
        int kb = kt * 64;
        int cur = kt & 1, nxt = cur ^ 1;
        if (kt + 1 < nkt) {
            int kb2 = kb + 64;
            __builtin_amdgcn_global_load_lds(
                (const AS1 void*)(gK + (size_t)(kb2 + srow) * 1024 + scol),
                (AS3 void*)(ldsK + nxt * 8192), 16, 0, 0);
            __builtin_amdgcn_global_load_lds(
                (const AS1 void*)(gV + (size_t)srow * 4096 + kb2 * 2 + scol),
                (AS3 void*)(ldsV + nxt * 8192), 16, 0, 0);
        }
        if (kb <= qmax) {
            const char* Kbuf = (const char*)Ks + cur * 8192;
            const char* Vbuf = (const char*)Vs + cur * 8192;
            f32x4 sc[2][2];
#pragma unroll
            for (int ks = 0; ks < 2; ks++)
                for (int kc = 0; kc < 2; kc++) {
                    int krow = ks * 32 + kc * 16 + lr;
                    bf16x8 k0 = *(const bf16x8*)(Kbuf + krow * 128 + ((lg * 16) ^ sw));
                    bf16x8 k1 = *(const bf16x8*)(Kbuf + krow * 128 + ((64 + lg * 16) ^ sw));
                    f32x4 z = {};
                    z = __builtin_amdgcn_mfma_f32_16x16x32_bf16(k0, q0, z, 0, 0, 0);
                    sc[ks][kc] = __builtin_amdgcn_mfma_f32_16x16x32_bf16(k1, q1, z, 0, 0, 0);
                }
            if (kb + 63 > qrow0) {
#pragma unroll
                for (int ks = 0; ks < 2; ks++)
                    for (int kc = 0; kc < 2; kc++)
                        for (int r = 0; r < 4; r++) {
                            int kg = kb + ks * 32 + kc * 16 + lg * 4 + r;
                            if (kg > qg) sc[ks][kc][r] = -1e30f;
                        }
            }
            float tmax = -3e38f;
#pragma unroll
            for (int ks = 0; ks < 2; ks++)
                for (int kc = 0; kc < 2; kc++)
                    for (int r = 0; r < 4; r++) tmax = fmaxf(tmax, sc[ks][kc][r]);
            tmax = fmaxf(tmax, __shfl_xor(tmax, 16));
            tmax = fmaxf(tmax, __shfl_xor(tmax, 32));
            if (!__all(tmax <= m)) {
                float mn = fmaxf(m, tmax);
                float al = __expf(m - mn);
                m = mn;
                ll *= al;
#pragma unroll
                for (int fn = 0; fn < 4; fn++)
                    for (int r = 0; r < 4; r++) o[fn][r] *= al;
            }
            float rsum = 0.0f;
#pragma unroll
            for (int ks = 0; ks < 2; ks++)
                for (int kc = 0; kc < 2; kc++) {
                    bf16x4 pk;
                    for (int r = 0; r < 4; r++) {
                        float pv = __expf(sc[ks][kc][r] - m);
                        rsum += pv;
                        pk[r] = (bf16)pv;
                    }
                    *(bf16x4*)&plds[w][lr][ks * 32 + kc * 16 + lg * 4] = pk;
                }
            ll += rsum;
            bf16x8 vf[2][4];
#pragma unroll
            for (int ks = 0; ks < 2; ks++)
                for (int fn = 0; fn < 4; fn++) {
                    int drow = fn * 16 + lr;
                    vf[ks][fn] = *(const bf16x8*)(Vbuf + drow * 128 + ((ks * 64 + lg * 16) ^ sw));
                }
            asm volatile("s_waitcnt lgkmcnt(0)" ::: "memory");
            __builtin_amdgcn_sched_barrier(0);
            bf16x8 pa0 = *(const bf16x8*)&plds[w][lr][lg * 8];
            bf16x8 pa1 = *(const bf16x8*)&plds[w][lr][32 + lg * 8];
#pragma unroll
            for (int fn = 0; fn < 4; fn++)
                o[fn] = __builtin_amdgcn_mfma_f32_16x16x32_bf16(vf[0][fn], pa0, o[fn], 0, 0, 0);
#pragma unroll
            for (int fn = 0; fn < 4; fn++)
                o[fn] = __builtin_amdgcn_mfma_f32_16x16x32_bf16(vf[1][fn], pa1, o[fn], 0, 0, 0);
        }
        __syncthreads();
    }

    ll += __shfl_xor(ll, 16);
    ll += __shfl_xor(ll, 32);
    float rinv = 1.0f / ll;
    for (int fn = 0; fn < 4; fn++) {
        bf16x4 ov;
        for (int r = 0; r < 4; r++) ov[r] = (bf16)(o[fn][r] * rinv);
        *(bf16x4*)&O[(size_t)qg * 2048 + h * 64 + fn * 16 + lg * 4] = ov;
    }
}

// ---------------------------------------------------------------------------
extern "C" void kernel_launch(void* const* d_in, const int* in_sizes, int n_in,
                              void* d_out, int out_size, void* d_ws, size_t ws_size,
                              hipStream_t stream) {
    const float* hidden = (const float*)d_in[0];
    const int*   pos    = (const int*)d_in[1];   // harness converts int64 -> int32
    const float* cosb   = (const float*)d_in[2];
    const float* sinb   = (const float*)d_in[3];
    const float* ln_w   = (const float*)d_in[4];
    const float* ln_b   = (const float*)d_in[5];
    const float* wq     = (const float*)d_in[6];
    const float* wk     = (const float*)d_in[7];
    const float* wv     = (const float*)d_in[8];
    const float* wo     = (const float*)d_in[9];
    const float* twq    = (const float*)d_in[10];
    const float* twv    = (const float*)d_in[11];
    const float* alpha  = (const float*)d_in[12];
    const float* up_w   = (const float*)d_in[13];
    const float* up_b   = (const float*)d_in[14];
    const float* down_w = (const float*)d_in[15];
    const float* down_b = (const float*)d_in[16];
    float* out = (float*)d_out;

    char* p = (char*)d_ws;
    auto alloc = [&](size_t n) -> char* {
        char* r = p;
        p += (n + 255) & ~(size_t)255;
        return r;
    };
    bf16* wqkvT = (bf16*)alloc((size_t)3072 * 2048 * 2);
    bf16* woT   = (bf16*)alloc((size_t)2048 * 2048 * 2);
    bf16* upT   = (bf16*)alloc((size_t)8192 * 2048 * 2);
    bf16* downT = (bf16*)alloc((size_t)2048 * 8192 * 2);
    bf16* xn    = (bf16*)alloc((size_t)2048 * 2048 * 2);
    float* qkv  = (float*)alloc((size_t)2048 * 3072 * 4);
    float* tauq = (float*)alloc((size_t)2048 * 32 * 4);
    float* tauv = (float*)alloc((size_t)2048 * 32 * 4);
    bf16* Qr    = (bf16*)alloc((size_t)2048 * 2048 * 2);
    bf16* Kr    = (bf16*)alloc((size_t)2048 * 512 * 2);
    bf16* Vt    = (bf16*)alloc((size_t)8 * 64 * 2048 * 2);
    bf16* aout  = (bf16*)alloc((size_t)2048 * 2048 * 2);
    bf16* hbuf  = (bf16*)alloc((size_t)2048 * 8192 * 2);
    float* Wp   = (float*)alloc((size_t)2 * 2048 * 2048 * 4);
    float* Pp   = (float*)alloc((size_t)2 * 2048 * 2048 * 4);

    k_transpose<<<dim3(64, 64), 256, 0, stream>>>(wq, wqkvT, 2048, 2048, 2048);
    k_transpose<<<dim3(16, 64), 256, 0, stream>>>(wk, wqkvT + (size_t)2048 * 2048, 2048, 512, 2048);
    k_transpose<<<dim3(16, 64), 256, 0, stream>>>(wv, wqkvT + (size_t)2560 * 2048, 2048, 512, 2048);
    k_transpose<<<dim3(64, 64), 256, 0, stream>>>(wo, woT, 2048, 2048, 2048);
    k_transpose<<<dim3(256, 64), 256, 0, stream>>>(up_w, upT, 2048, 8192, 2048);
    k_transpose<<<dim3(64, 256), 256, 0, stream>>>(down_w, downT, 8192, 2048, 8192);

    k_ln<<<2048, 256, 0, stream>>>(hidden, ln_w, ln_b, xn);

    // qkv = xn @ [wq|wk|wv]
    k_gemm<0><<<dim3(24, 16, 1), 256, 0, stream>>>(xn, wqkvT, 2048, 3072, 2048, 2048,
                                                   qkv, nullptr, nullptr);

    k_tau<<<2048, 256, 0, stream>>>(qkv, twq, twv, alpha, pos, tauq, tauv);
    k_heads<<<512, 256, 0, stream>>>(qkv, cosb, sinb, tauq, tauv, Qr, Kr, Vt);

    k_attn<<<dim3(32, 16), 512, 0, stream>>>(Qr, Kr, Vt, aout);

    // wo partials: aout @ woT, split-K 2
    k_gemm<0><<<dim3(16, 16, 2), 256, 0, stream>>>(aout, woT, 2048, 2048, 2048, 1024,
                                                   Wp, nullptr, nullptr);
    // h = gelu_tanh(xn @ up_w + up_b)
    k_gemm<1><<<dim3(64, 16, 1), 256, 0, stream>>>(xn, upT, 2048, 8192, 2048, 2048,
                                                   nullptr, hbuf, up_b);
    // down partials: hbuf @ downT, split-K 2
    k_gemm<0><<<dim3(16, 16, 2), 256, 0, stream>>>(hbuf, downT, 2048, 2048, 8192, 4096,
                                                   Pp, nullptr, nullptr);
    // out = hidden + W0+W1 + P0+P1 + down_b
    k_final<<<4096, 256, 0, stream>>>(hidden, Wp, Wp + (size_t)2048 * 2048,
                                      Pp, Pp + (size_t)2048 * 2048, down_b, out);
}